// Round 2
// baseline (782.217 us; speedup 1.0000x reference)
//
#include <hip/hip_runtime.h>
#include <math.h>

// DisentangledStateEncoder on MI355X (gfx950).
//
// Phase 1 ("lane = row"): each thread owns one of the 262144 rows.
//   acc = x_row @ W1 + b1          (weights via wave-uniform s_load, x in regs)
//   h   = gelu(LN(acc))            (entirely within-lane, no shuffles/LDS)
//   preT[j][row]  = h @ Wc1_h + bc1   (stored transposed, coalesced)
//   ballT[i][row] = h @ W_inn + b_inn
//
// Phase 2: sequential scan over T=512; one wave per batch row, lane = hidden
//   unit. Reductions via DPP row_ror + ds_swizzle(xor16) + shfl_xor(32).
//
// B=512, T=512, D=128, H=64, S=5.

#define NROWS 262144
#define RS ((size_t)NROWS)

__device__ __forceinline__ float sigmoidf_(float v){ return 1.0f/(1.0f+expf(-v)); }

template<int CTRL>
__device__ __forceinline__ float dpp_add(float v){
    // v += rotate-within-16-lane-row(v)   (all source lanes valid for row_ror)
    return v + __int_as_float(__builtin_amdgcn_update_dpp(
        0, __float_as_int(v), CTRL, 0xF, 0xF, false));
}

__device__ __forceinline__ float swz_xor16(float v){
    // BitMode: and=0x1F, or=0, xor=16 -> lane ^ 16 (within 32-lane halves)
    return __int_as_float(__builtin_amdgcn_ds_swizzle(__float_as_int(v), 0x401F));
}

// all-64-lane sum of five independent values (interleaved for ILP)
__device__ __forceinline__ void allsum5(float& a, float& b, float& c, float& d, float& e){
    a = dpp_add<0x121>(a); b = dpp_add<0x121>(b); c = dpp_add<0x121>(c); d = dpp_add<0x121>(d); e = dpp_add<0x121>(e); // ror:1
    a = dpp_add<0x122>(a); b = dpp_add<0x122>(b); c = dpp_add<0x122>(c); d = dpp_add<0x122>(d); e = dpp_add<0x122>(e); // ror:2
    a = dpp_add<0x124>(a); b = dpp_add<0x124>(b); c = dpp_add<0x124>(c); d = dpp_add<0x124>(d); e = dpp_add<0x124>(e); // ror:4
    a = dpp_add<0x128>(a); b = dpp_add<0x128>(b); c = dpp_add<0x128>(c); d = dpp_add<0x128>(d); e = dpp_add<0x128>(e); // ror:8
    a += swz_xor16(a); b += swz_xor16(b); c += swz_xor16(c); d += swz_xor16(d); e += swz_xor16(e);
    a += __shfl_xor(a, 32, 64); b += __shfl_xor(b, 32, 64); c += __shfl_xor(c, 32, 64);
    d += __shfl_xor(d, 32, 64); e += __shfl_xor(e, 32, 64);
}

// ---------------------------------------------------------------- phase 1
// 1024 blocks x 256 threads; thread t of block b owns row b*256+t.
__global__ __launch_bounds__(256, 3) void dse_phase1(
    const float* __restrict__ x,
    const float* __restrict__ W1,
    const float* __restrict__ b1,
    const float* __restrict__ ln_g,
    const float* __restrict__ ln_b,
    const float* __restrict__ W_inn,
    const float* __restrict__ b_inn,
    const float* __restrict__ Wc1,
    const float* __restrict__ bc1,
    float* __restrict__ preT,
    float* __restrict__ ballT)
{
    const int row = blockIdx.x*256 + threadIdx.x;
    const float* xrow = x + (size_t)row*128;

    // ---- GEMM1: acc[j] = b1[j] + sum_k x[k] * W1[k][j]
    float acc[64];
    #pragma unroll
    for (int j = 0; j < 64; ++j) acc[j] = b1[j];          // uniform -> s_load

    for (int kc = 0; kc < 8; ++kc) {                       // runtime loop (I$)
        float xc[16];
        #pragma unroll
        for (int u = 0; u < 4; ++u) {
            float4 v = *(const float4*)&xrow[kc*16 + u*4];
            xc[u*4+0]=v.x; xc[u*4+1]=v.y; xc[u*4+2]=v.z; xc[u*4+3]=v.w;
        }
        #pragma unroll
        for (int kk = 0; kk < 16; ++kk) {
            const float* wr = W1 + (size_t)(kc*16 + kk)*64;   // uniform row
            #pragma unroll
            for (int j = 0; j < 64; ++j)
                acc[j] = fmaf(wr[j], xc[kk], acc[j]);      // SGPR * VGPR + VGPR
        }
    }

    // ---- LayerNorm over the 64 outputs (within-lane)
    float s = 0.f, sq = 0.f;
    #pragma unroll
    for (int j = 0; j < 64; ++j) { s += acc[j]; sq = fmaf(acc[j], acc[j], sq); }
    const float mu  = s * (1.0f/64.0f);
    const float var = fmaf(-mu, mu, sq * (1.0f/64.0f));
    const float rstd = 1.0f / sqrtf(var + 1e-5f);

    // ---- gelu (exact erf form)
    float h[64];
    #pragma unroll
    for (int j = 0; j < 64; ++j) {
        float hn = fmaf((acc[j] - mu) * rstd, ln_g[j], ln_b[j]);
        h[j] = 0.5f * hn * (1.0f + erff(hn * 0.70710678118654752f));
    }

    // ---- b_all[i] = b_inn[i] + sum_j h[j] * W_inn[j][i]
    float bacc[5];
    #pragma unroll
    for (int i = 0; i < 5; ++i) bacc[i] = b_inn[i];
    #pragma unroll
    for (int j = 0; j < 64; ++j) {
        const float* wi = W_inn + (size_t)j*5;             // uniform
        #pragma unroll
        for (int i = 0; i < 5; ++i) bacc[i] = fmaf(wi[i], h[j], bacc[i]);
    }
    #pragma unroll
    for (int i = 0; i < 5; ++i) ballT[(size_t)i*RS + row] = bacc[i];

    // ---- GEMM2: pre[j2] = bc1[j2] + sum_k h[k] * Wc1[(5+k)][j2]; store transposed
    for (int jb = 0; jb < 4; ++jb) {                       // runtime loop
        float a2[16];
        #pragma unroll
        for (int i = 0; i < 16; ++i) a2[i] = bc1[jb*16 + i];
        #pragma unroll
        for (int k = 0; k < 64; ++k) {
            const float* wr = Wc1 + (size_t)(5 + k)*64 + jb*16;   // uniform
            #pragma unroll
            for (int i = 0; i < 16; ++i) a2[i] = fmaf(wr[i], h[k], a2[i]);
        }
        #pragma unroll
        for (int i = 0; i < 16; ++i)
            preT[(size_t)(jb*16 + i)*RS + row] = a2[i];
    }
}

// ---------------------------------------------------------------- phase 2
// 512 blocks x 64 threads; block = batch row, lane = hidden unit.
__global__ __launch_bounds__(64) void dse_phase2(
    const float* __restrict__ preT,
    const float* __restrict__ ballT,
    const float* __restrict__ Wc1,
    const float* __restrict__ Wc2,
    const float* __restrict__ bc2,
    const float* __restrict__ corr_scale,
    const float* __restrict__ raw_aL,
    const float* __restrict__ raw_aT,
    const float* __restrict__ raw_g,
    const float* __restrict__ raw_aR,
    const float* __restrict__ omega,
    float* __restrict__ out)
{
    const int lane = threadIdx.x;
    const int b    = blockIdx.x;

    const float w0c = Wc1[0*64+lane];
    const float w1c = Wc1[1*64+lane];
    const float w2c = Wc1[2*64+lane];
    const float w3c = Wc1[3*64+lane];
    const float w4c = Wc1[4*64+lane];
    const float v0 = Wc2[lane*5+0];
    const float v1 = Wc2[lane*5+1];
    const float v2 = Wc2[lane*5+2];
    const float v3 = Wc2[lane*5+3];
    const float v4 = Wc2[lane*5+4];
    const float c0 = bc2[0], c1 = bc2[1], c2 = bc2[2], c3 = bc2[3], c4 = bc2[4];

    const float corr = corr_scale[0];
    const float aL = sigmoidf_(raw_aL[0])*0.15f + 0.85f;
    const float aT = sigmoidf_(raw_aT[0])*0.25f + 0.70f;
    const float gg = sigmoidf_(raw_g [0])*0.20f + 0.80f;
    const float aR = sigmoidf_(raw_aR[0])*0.40f;
    const float om = omega[0];
    const float gc  = gg*cosf(om);
    const float gs  = gg*sinf(om);
    const float ngs = -gs;

    const float* prow = preT  + (size_t)lane*RS + (size_t)b*512;  // per-lane stream
    const float* bb   = ballT + (size_t)b*512;                    // uniform streams

    float s0=0.f, s1=0.f, s2=0.f, s3=0.f, s4=0.f;

    // 4-step blocks, one block prefetched ahead
    float pc[4];
    float bq[5][4];
    {
        float4 pv = *(const float4*)&prow[0];
        pc[0]=pv.x; pc[1]=pv.y; pc[2]=pv.z; pc[3]=pv.w;
        #pragma unroll
        for (int i = 0; i < 5; ++i) {
            float4 t = *(const float4*)&bb[(size_t)i*RS + 0];
            bq[i][0]=t.x; bq[i][1]=t.y; bq[i][2]=t.z; bq[i][3]=t.w;
        }
    }

    for (int tb = 0; tb < 128; ++tb) {
        const int tn = (tb < 127 ? tb + 1 : tb) * 4;
        float4 pvn = *(const float4*)&prow[tn];
        float4 bn0 = *(const float4*)&bb[(size_t)0*RS + tn];
        float4 bn1 = *(const float4*)&bb[(size_t)1*RS + tn];
        float4 bn2 = *(const float4*)&bb[(size_t)2*RS + tn];
        float4 bn3 = *(const float4*)&bb[(size_t)3*RS + tn];
        float4 bn4 = *(const float4*)&bb[(size_t)4*RS + tn];

        #pragma unroll
        for (int q = 0; q < 4; ++q) {
            // gated state + b_t
            float sl0 = fmaf(s0, aL, bq[0][q]);
            float sl1 = fmaf(s1, aT, bq[1][q]);
            float sl2 = fmaf(s2, gc,  fmaf(s3, gs,  bq[2][q]));
            float sl3 = fmaf(s3, gc,  fmaf(s2, ngs, bq[3][q]));
            float sl4 = fmaf(s4, aR, bq[4][q]);

            // u = pre + s_lin @ Wc1_s   (tree form)
            float u01 = fmaf(sl1, w1c, sl0*w0c);
            float u23 = fmaf(sl3, w3c, sl2*w2c);
            float u4p = fmaf(sl4, w4c, pc[q]);
            float u   = (u01 + u23) + u4p;
            float hm  = 0.5f*u*(1.0f + erff(u*0.70710678118654752f));

            // hmlp @ Wc2 -> 5 all-lane sums
            float p0 = hm*v0, p1 = hm*v1, p2 = hm*v2, p3 = hm*v3, p4 = hm*v4;
            allsum5(p0, p1, p2, p3, p4);

            s0 = fmaf(corr, tanhf(p0 + c0), sl0);
            s1 = fmaf(corr, tanhf(p1 + c1), sl1);
            s2 = fmaf(corr, tanhf(p2 + c2), sl2);
            s3 = fmaf(corr, tanhf(p3 + c3), sl3);
            s4 = fmaf(corr, tanhf(p4 + c4), sl4);
        }

        pc[0]=pvn.x; pc[1]=pvn.y; pc[2]=pvn.z; pc[3]=pvn.w;
        bq[0][0]=bn0.x; bq[0][1]=bn0.y; bq[0][2]=bn0.z; bq[0][3]=bn0.w;
        bq[1][0]=bn1.x; bq[1][1]=bn1.y; bq[1][2]=bn1.z; bq[1][3]=bn1.w;
        bq[2][0]=bn2.x; bq[2][1]=bn2.y; bq[2][2]=bn2.z; bq[2][3]=bn2.w;
        bq[3][0]=bn3.x; bq[3][1]=bn3.y; bq[3][2]=bn3.z; bq[3][3]=bn3.w;
        bq[4][0]=bn4.x; bq[4][1]=bn4.y; bq[4][2]=bn4.z; bq[4][3]=bn4.w;
    }

    if (lane < 5) {
        float v = (lane==0)?s0 : (lane==1)?s1 : (lane==2)?s2 : (lane==3)?s3 : s4;
        out[b*5 + lane] = v;
    }
}

// ---------------------------------------------------------------- launch
extern "C" void kernel_launch(void* const* d_in, const int* in_sizes, int n_in,
                              void* d_out, int out_size, void* d_ws, size_t ws_size,
                              hipStream_t stream) {
    const float* x     = (const float*)d_in[0];
    const float* W1    = (const float*)d_in[1];
    const float* b1    = (const float*)d_in[2];
    const float* ln_g  = (const float*)d_in[3];
    const float* ln_b  = (const float*)d_in[4];
    const float* W_inn = (const float*)d_in[5];
    const float* b_inn = (const float*)d_in[6];
    const float* Wc1   = (const float*)d_in[7];
    const float* bc1   = (const float*)d_in[8];
    const float* Wc2   = (const float*)d_in[9];
    const float* bc2   = (const float*)d_in[10];
    const float* corr  = (const float*)d_in[11];
    const float* raL   = (const float*)d_in[12];
    const float* raT   = (const float*)d_in[13];
    const float* rg    = (const float*)d_in[14];
    const float* raR   = (const float*)d_in[15];
    const float* om    = (const float*)d_in[16];

    float* preT  = (float*)d_ws;                 // 64 * 262144 f32 = 64 MiB
    float* ballT = preT + (size_t)64*RS;         //  5 * 262144 f32 = 5 MiB

    dse_phase1<<<1024, 256, 0, stream>>>(x, W1, b1, ln_g, ln_b, W_inn, b_inn,
                                         Wc1, bc1, preT, ballT);
    dse_phase2<<<512, 64, 0, stream>>>(preT, ballT, Wc1, Wc2, bc2, corr,
                                       raL, raT, rg, raR, om, (float*)d_out);
}

// Round 5
// 555.879 us; speedup vs baseline: 1.4072x; 1.4072x over previous
//
#include <hip/hip_runtime.h>
#include <math.h>

// DisentangledStateEncoder on MI355X (gfx950).
// Phase 1 (MFMA bf16x3): per 64-row tile, one wave:
//   y = x@W1 + b1 (MFMA, bf16 hi/lo 3-term), LN+gelu fused epilogue (DPP-16),
//   ball = h@W_inn + b_inn (VALU+DPP), pre = h@Wc1_h + bc1 (MFMA via LDS h).
// Phase 2: sequential scan, one wave per batch row, coalesced row-major reads.
// B=512, T=512, D=128, H=64, S=5.

#define RS ((size_t)262144)

typedef __attribute__((ext_vector_type(8))) short bf16x8;
typedef __attribute__((ext_vector_type(4))) float f32x4;

__device__ __forceinline__ unsigned bf16_rne(float f){
    unsigned u = __float_as_uint(f);
    return (u + 0x7FFFu + ((u >> 16) & 1u)) >> 16;
}
__device__ __forceinline__ float bf16_to_f(unsigned h){ return __uint_as_float(h << 16); }
__device__ __forceinline__ float sigmoidf_(float v){ return 1.0f/(1.0f+expf(-v)); }

template<int CTRL>
__device__ __forceinline__ float dpp_add(float v){
    return v + __int_as_float(__builtin_amdgcn_update_dpp(
        0, __float_as_int(v), CTRL, 0xF, 0xF, false));
}
// full sum over each 16-lane row (all lanes receive it)
__device__ __forceinline__ float sum16(float v){
    v = dpp_add<0x121>(v); v = dpp_add<0x122>(v);
    v = dpp_add<0x124>(v); v = dpp_add<0x128>(v);
    return v;
}
__device__ __forceinline__ float swz_xor16(float v){
    return __int_as_float(__builtin_amdgcn_ds_swizzle(__float_as_int(v), 0x401F));
}
__device__ __forceinline__ void allsum5(float& a, float& b, float& c, float& d, float& e){
    a = dpp_add<0x121>(a); b = dpp_add<0x121>(b); c = dpp_add<0x121>(c); d = dpp_add<0x121>(d); e = dpp_add<0x121>(e);
    a = dpp_add<0x122>(a); b = dpp_add<0x122>(b); c = dpp_add<0x122>(c); d = dpp_add<0x122>(d); e = dpp_add<0x122>(e);
    a = dpp_add<0x124>(a); b = dpp_add<0x124>(b); c = dpp_add<0x124>(c); d = dpp_add<0x124>(d); e = dpp_add<0x124>(e);
    a = dpp_add<0x128>(a); b = dpp_add<0x128>(b); c = dpp_add<0x128>(c); d = dpp_add<0x128>(d); e = dpp_add<0x128>(e);
    a += swz_xor16(a); b += swz_xor16(b); c += swz_xor16(c); d += swz_xor16(d); e += swz_xor16(e);
    a += __shfl_xor(a, 32, 64); b += __shfl_xor(b, 32, 64); c += __shfl_xor(c, 32, 64);
    d += __shfl_xor(d, 32, 64); e += __shfl_xor(e, 32, 64);
}

// ------------------------------------------------ weight pack (frag order)
// mfma_f32_16x16x32_bf16 A/B frag: lane l, elem e -> k = 4*(l>>4)+(e&3)+16*(e>>2),
// row/col = l&15.  Packed as [frag][half(hi,lo)][lane][8 shorts].
__global__ void dse_pack(const float* __restrict__ W1, const float* __restrict__ Wc1,
                         unsigned short* __restrict__ pw1, unsigned short* __restrict__ pw2){
    int t = blockIdx.x*256 + threadIdx.x;         // 0..1535
    if (t >= 1536) return;
    int lane = t & 63, frag = t >> 6;             // frag 0-15: W1, 16-23: W2
    int q = lane >> 4, m = lane & 15;
    int f  = (frag < 16) ? frag : frag - 16;
    int ks = f >> 2, nf = f & 3;
    unsigned short hi[8], lo[8];
    #pragma unroll
    for (int e = 0; e < 8; ++e){
        int k = ks*32 + 4*q + (e & 3) + 16*(e >> 2);
        float v = (frag < 16) ? W1[(size_t)k*64 + nf*16 + m]
                              : Wc1[(size_t)(5 + k)*64 + nf*16 + m];
        unsigned h = bf16_rne(v);
        hi[e] = (unsigned short)h;
        lo[e] = (unsigned short)bf16_rne(v - bf16_to_f(h));
    }
    unsigned short* dst = (frag < 16) ? pw1 : pw2;
    size_t b0 = ((size_t)(f*2 + 0)*64 + lane)*8;
    size_t b1 = ((size_t)(f*2 + 1)*64 + lane)*8;
    #pragma unroll
    for (int e = 0; e < 8; ++e){ dst[b0+e] = hi[e]; dst[b1+e] = lo[e]; }
}

// ------------------------------------------------ phase 1: 4096 blocks x 64
__global__ __launch_bounds__(64, 2) void dse_mfma1(
    const float* __restrict__ x,
    const unsigned short* __restrict__ pw1,
    const unsigned short* __restrict__ pw2,
    const float* __restrict__ b1, const float* __restrict__ ln_g,
    const float* __restrict__ ln_b, const float* __restrict__ W_inn,
    const float* __restrict__ b_inn, const float* __restrict__ bc1,
    float* __restrict__ pre, float* __restrict__ ball)
{
    __shared__ unsigned hbuf[64*64];          // h packed (hi<<16)|lo, swizzled
    const int lane = threadIdx.x;
    const int m = lane & 15, q = lane >> 4;
    const size_t row0 = (size_t)blockIdx.x * 64;
    const float* xb = x + row0*128;

    f32x4 acc[4][4];
    #pragma unroll
    for (int a = 0; a < 4; ++a)
        #pragma unroll
        for (int b = 0; b < 4; ++b) acc[a][b] = (f32x4){0.f,0.f,0.f,0.f};

    // ---- GEMM1: K=128 in 4 steps of 32, 3-term bf16 split
    #pragma unroll
    for (int ks = 0; ks < 4; ++ks){
        bf16x8 Bhi[4], Blo[4];
        #pragma unroll
        for (int nf = 0; nf < 4; ++nf){
            int fr = ks*4 + nf;
            Bhi[nf] = *(const bf16x8*)(pw1 + ((size_t)(fr*2+0)*64 + lane)*8);
            Blo[nf] = *(const bf16x8*)(pw1 + ((size_t)(fr*2+1)*64 + lane)*8);
        }
        bf16x8 Ahi[4], Alo[4];
        #pragma unroll
        for (int mf = 0; mf < 4; ++mf){
            const float* ap = xb + (size_t)(mf*16 + m)*128 + ks*32 + q*4;
            float4 L = *(const float4*)ap;
            float4 H = *(const float4*)(ap + 16);
            float v[8] = {L.x,L.y,L.z,L.w,H.x,H.y,H.z,H.w};
            bf16x8 h8, l8;
            #pragma unroll
            for (int e = 0; e < 8; ++e){
                unsigned hb = bf16_rne(v[e]);
                h8[e] = (short)hb;
                l8[e] = (short)bf16_rne(v[e] - bf16_to_f(hb));
            }
            Ahi[mf] = h8; Alo[mf] = l8;
        }
        #pragma unroll
        for (int mf = 0; mf < 4; ++mf)
            #pragma unroll
            for (int nf = 0; nf < 4; ++nf){
                acc[mf][nf] = __builtin_amdgcn_mfma_f32_16x16x32_bf16(Ahi[mf], Bhi[nf], acc[mf][nf], 0,0,0);
                acc[mf][nf] = __builtin_amdgcn_mfma_f32_16x16x32_bf16(Ahi[mf], Blo[nf], acc[mf][nf], 0,0,0);
                acc[mf][nf] = __builtin_amdgcn_mfma_f32_16x16x32_bf16(Alo[mf], Bhi[nf], acc[mf][nf], 0,0,0);
            }
    }

    // ---- per-lane params (col = nf*16 + m)
    float b1c[4], gcl[4], bcl[4], bc1c[4], wi[4][5];
    #pragma unroll
    for (int nf = 0; nf < 4; ++nf){
        int col = nf*16 + m;
        b1c[nf] = b1[col]; gcl[nf] = ln_g[col]; bcl[nf] = ln_b[col]; bc1c[nf] = bc1[col];
        #pragma unroll
        for (int i = 0; i < 5; ++i) wi[nf][i] = W_inn[(size_t)col*5 + i];
    }
    const float binsel = (m==0)?b_inn[0]:(m==1)?b_inn[1]:(m==2)?b_inn[2]:(m==3)?b_inn[3]:b_inn[4];

    // ---- epilogue per mf: bias + LN + gelu + ball + h->LDS
    // C layout: row = mf*16 + q*4 + e, col = nf*16 + m
    #pragma unroll
    for (int mf = 0; mf < 4; ++mf){
        float sum_[4], sq_[4];
        #pragma unroll
        for (int e = 0; e < 4; ++e){
            float s = 0.f, qq = 0.f;
            #pragma unroll
            for (int nf = 0; nf < 4; ++nf){
                float y = acc[mf][nf][e] + b1c[nf];
                acc[mf][nf][e] = y;
                s += y; qq = fmaf(y, y, qq);
            }
            sum_[e] = s; sq_[e] = qq;
        }
        #pragma unroll
        for (int e = 0; e < 4; ++e){ sum_[e] = sum16(sum_[e]); sq_[e] = sum16(sq_[e]); }

        float pb[4][5];
        #pragma unroll
        for (int e = 0; e < 4; ++e){
            float mu  = sum_[e] * (1.0f/64.0f);
            float var = fmaf(-mu, mu, sq_[e] * (1.0f/64.0f));
            float rs  = 1.0f / sqrtf(var + 1e-5f);
            #pragma unroll
            for (int i = 0; i < 5; ++i) pb[e][i] = 0.f;
            int r = mf*16 + q*4 + e;
            #pragma unroll
            for (int nf = 0; nf < 4; ++nf){
                float hn = fmaf((acc[mf][nf][e] - mu)*rs, gcl[nf], bcl[nf]);
                float ge = 0.5f*hn*(1.0f + erff(hn*0.70710678118654752f));
                unsigned hb = bf16_rne(ge);
                unsigned lb = bf16_rne(ge - bf16_to_f(hb));
                int c = nf*16 + m;
                hbuf[r*64 + (c ^ ((r & 7) << 2))] = (hb << 16) | lb;
                #pragma unroll
                for (int i = 0; i < 5; ++i) pb[e][i] = fmaf(ge, wi[nf][i], pb[e][i]);
            }
        }
        #pragma unroll
        for (int e = 0; e < 4; ++e)
            #pragma unroll
            for (int i = 0; i < 5; ++i) pb[e][i] = sum16(pb[e][i]);
        if (m < 5){
            #pragma unroll
            for (int e = 0; e < 4; ++e){
                int r = mf*16 + q*4 + e;
                float v = (m==0)?pb[e][0]:(m==1)?pb[e][1]:(m==2)?pb[e][2]:(m==3)?pb[e][3]:pb[e][4];
                ball[(row0 + r)*5 + m] = v + binsel;
            }
        }
    }
    __syncthreads();

    // ---- GEMM2: pre = h @ Wc1_h + bc1  (K=64, 2 steps, 3-term)
    f32x4 a2[4][4];
    #pragma unroll
    for (int a = 0; a < 4; ++a)
        #pragma unroll
        for (int b = 0; b < 4; ++b) a2[a][b] = (f32x4){0.f,0.f,0.f,0.f};

    #pragma unroll
    for (int ks = 0; ks < 2; ++ks){
        bf16x8 B2h[4], B2l[4];
        #pragma unroll
        for (int nf = 0; nf < 4; ++nf){
            int fr = ks*4 + nf;
            B2h[nf] = *(const bf16x8*)(pw2 + ((size_t)(fr*2+0)*64 + lane)*8);
            B2l[nf] = *(const bf16x8*)(pw2 + ((size_t)(fr*2+1)*64 + lane)*8);
        }
        bf16x8 A2h[4], A2l[4];
        #pragma unroll
        for (int mf = 0; mf < 4; ++mf){
            int r   = mf*16 + m;
            int sw  = (r & 7) << 2;
            int jb0 = ks*32 + 4*q;
            uint4 w0 = *(const uint4*)&hbuf[r*64 + (jb0 ^ sw)];
            uint4 w1 = *(const uint4*)&hbuf[r*64 + ((jb0 + 16) ^ sw)];
            int4 hv = make_int4(
                (int)__builtin_amdgcn_perm(w0.y, w0.x, 0x07060302u),
                (int)__builtin_amdgcn_perm(w0.w, w0.z, 0x07060302u),
                (int)__builtin_amdgcn_perm(w1.y, w1.x, 0x07060302u),
                (int)__builtin_amdgcn_perm(w1.w, w1.z, 0x07060302u));
            int4 lv = make_int4(
                (int)__builtin_amdgcn_perm(w0.y, w0.x, 0x05040100u),
                (int)__builtin_amdgcn_perm(w0.w, w0.z, 0x05040100u),
                (int)__builtin_amdgcn_perm(w1.y, w1.x, 0x05040100u),
                (int)__builtin_amdgcn_perm(w1.w, w1.z, 0x05040100u));
            A2h[mf] = __builtin_bit_cast(bf16x8, hv);
            A2l[mf] = __builtin_bit_cast(bf16x8, lv);
        }
        #pragma unroll
        for (int mf = 0; mf < 4; ++mf)
            #pragma unroll
            for (int nf = 0; nf < 4; ++nf){
                a2[mf][nf] = __builtin_amdgcn_mfma_f32_16x16x32_bf16(A2h[mf], B2h[nf], a2[mf][nf], 0,0,0);
                a2[mf][nf] = __builtin_amdgcn_mfma_f32_16x16x32_bf16(A2h[mf], B2l[nf], a2[mf][nf], 0,0,0);
                a2[mf][nf] = __builtin_amdgcn_mfma_f32_16x16x32_bf16(A2l[mf], B2h[nf], a2[mf][nf], 0,0,0);
            }
    }
    #pragma unroll
    for (int mf = 0; mf < 4; ++mf)
        #pragma unroll
        for (int nf = 0; nf < 4; ++nf)
            #pragma unroll
            for (int e = 0; e < 4; ++e)
                pre[(row0 + mf*16 + q*4 + e)*64 + nf*16 + m] = a2[mf][nf][e] + bc1c[nf];
}

// ------------------------------------------------ phase 2: 512 blocks x 64
__global__ __launch_bounds__(64) void dse_phase2(
    const float* __restrict__ pre,
    const float* __restrict__ ball,
    const float* __restrict__ Wc1,
    const float* __restrict__ Wc2,
    const float* __restrict__ bc2,
    const float* __restrict__ corr_scale,
    const float* __restrict__ raw_aL,
    const float* __restrict__ raw_aT,
    const float* __restrict__ raw_g,
    const float* __restrict__ raw_aR,
    const float* __restrict__ omega,
    float* __restrict__ out)
{
    const int lane = threadIdx.x;
    const int b    = blockIdx.x;

    const float w0c = Wc1[0*64+lane], w1c = Wc1[1*64+lane], w2c = Wc1[2*64+lane];
    const float w3c = Wc1[3*64+lane], w4c = Wc1[4*64+lane];
    const float v0 = Wc2[lane*5+0], v1 = Wc2[lane*5+1], v2 = Wc2[lane*5+2];
    const float v3 = Wc2[lane*5+3], v4 = Wc2[lane*5+4];
    const float c0 = bc2[0], c1 = bc2[1], c2 = bc2[2], c3 = bc2[3], c4 = bc2[4];

    const float corr = corr_scale[0];
    const float aL = sigmoidf_(raw_aL[0])*0.15f + 0.85f;
    const float aT = sigmoidf_(raw_aT[0])*0.25f + 0.70f;
    const float gg = sigmoidf_(raw_g [0])*0.20f + 0.80f;
    const float aR = sigmoidf_(raw_aR[0])*0.40f;
    const float om = omega[0];
    const float gc  = gg*cosf(om), gs = gg*sinf(om), ngs = -gs;

    const float* prow = pre  + (size_t)b*512*64 + lane;   // coalesced per step
    const float* bb   = ball + (size_t)b*512*5;           // uniform per step

    float s0=0.f, s1=0.f, s2=0.f, s3=0.f, s4=0.f;

    float pc[4], bf[20];
    #pragma unroll
    for (int d = 0; d < 4; ++d) pc[d] = prow[d*64];
    #pragma unroll
    for (int w = 0; w < 5; ++w){
        float4 t = *(const float4*)&bb[w*4];
        bf[w*4+0]=t.x; bf[w*4+1]=t.y; bf[w*4+2]=t.z; bf[w*4+3]=t.w;
    }

    for (int tb = 0; tb < 128; ++tb) {
        const int tn = (tb < 127 ? tb + 1 : tb) * 4;
        float pn[4];
        #pragma unroll
        for (int d = 0; d < 4; ++d) pn[d] = prow[(size_t)(tn + d)*64];
        float4 n0 = *(const float4*)&bb[(size_t)tn*5 +  0];
        float4 n1 = *(const float4*)&bb[(size_t)tn*5 +  4];
        float4 n2 = *(const float4*)&bb[(size_t)tn*5 +  8];
        float4 n3 = *(const float4*)&bb[(size_t)tn*5 + 12];
        float4 n4 = *(const float4*)&bb[(size_t)tn*5 + 16];

        #pragma unroll
        for (int q = 0; q < 4; ++q) {
            float sl0 = fmaf(s0, aL, bf[q*5+0]);
            float sl1 = fmaf(s1, aT, bf[q*5+1]);
            float sl2 = fmaf(s2, gc,  fmaf(s3, gs,  bf[q*5+2]));
            float sl3 = fmaf(s3, gc,  fmaf(s2, ngs, bf[q*5+3]));
            float sl4 = fmaf(s4, aR, bf[q*5+4]);

            float u01 = fmaf(sl1, w1c, sl0*w0c);
            float u23 = fmaf(sl3, w3c, sl2*w2c);
            float u4p = fmaf(sl4, w4c, pc[q]);
            float u   = (u01 + u23) + u4p;
            float hm  = 0.5f*u*(1.0f + erff(u*0.70710678118654752f));

            float p0 = hm*v0, p1 = hm*v1, p2 = hm*v2, p3 = hm*v3, p4 = hm*v4;
            allsum5(p0, p1, p2, p3, p4);

            s0 = fmaf(corr, tanhf(p0 + c0), sl0);
            s1 = fmaf(corr, tanhf(p1 + c1), sl1);
            s2 = fmaf(corr, tanhf(p2 + c2), sl2);
            s3 = fmaf(corr, tanhf(p3 + c3), sl3);
            s4 = fmaf(corr, tanhf(p4 + c4), sl4);
        }

        #pragma unroll
        for (int d = 0; d < 4; ++d) pc[d] = pn[d];
        bf[0]=n0.x; bf[1]=n0.y; bf[2]=n0.z; bf[3]=n0.w;
        bf[4]=n1.x; bf[5]=n1.y; bf[6]=n1.z; bf[7]=n1.w;
        bf[8]=n2.x; bf[9]=n2.y; bf[10]=n2.z; bf[11]=n2.w;
        bf[12]=n3.x; bf[13]=n3.y; bf[14]=n3.z; bf[15]=n3.w;
        bf[16]=n4.x; bf[17]=n4.y; bf[18]=n4.z; bf[19]=n4.w;
    }

    if (lane < 5) {
        float v = (lane==0)?s0 : (lane==1)?s1 : (lane==2)?s2 : (lane==3)?s3 : s4;
        out[b*5 + lane] = v;
    }
}

// ------------------------------------------------ launch
extern "C" void kernel_launch(void* const* d_in, const int* in_sizes, int n_in,
                              void* d_out, int out_size, void* d_ws, size_t ws_size,
                              hipStream_t stream) {
    const float* x     = (const float*)d_in[0];
    const float* W1    = (const float*)d_in[1];
    const float* b1    = (const float*)d_in[2];
    const float* ln_g  = (const float*)d_in[3];
    const float* ln_b  = (const float*)d_in[4];
    const float* W_inn = (const float*)d_in[5];
    const float* b_inn = (const float*)d_in[6];
    const float* Wc1   = (const float*)d_in[7];
    const float* bc1   = (const float*)d_in[8];
    const float* Wc2   = (const float*)d_in[9];
    const float* bc2   = (const float*)d_in[10];
    const float* corr  = (const float*)d_in[11];
    const float* raL   = (const float*)d_in[12];
    const float* raT   = (const float*)d_in[13];
    const float* rg    = (const float*)d_in[14];
    const float* raR   = (const float*)d_in[15];
    const float* om    = (const float*)d_in[16];

    float* pre  = (float*)d_ws;                          // 64 MiB
    float* ball = pre + RS*64;                           // 5 MiB
    unsigned short* pw1 = (unsigned short*)(ball + RS*5);// 32 KiB (16 frags x2x64x8)
    unsigned short* pw2 = pw1 + 16*2*64*8;               // 16 KiB (8 frags x2x64x8)

    dse_pack<<<6, 256, 0, stream>>>(W1, Wc1, pw1, pw2);
    dse_mfma1<<<4096, 64, 0, stream>>>(x, pw1, pw2, b1, ln_g, ln_b, W_inn, b_inn,
                                       bc1, pre, ball);
    dse_phase2<<<512, 64, 0, stream>>>(pre, ball, Wc1, Wc2, bc2, corr,
                                       raL, raT, rg, raR, om, (float*)d_out);
}

// Round 8
// 457.677 us; speedup vs baseline: 1.7091x; 1.2146x over previous
//
#include <hip/hip_runtime.h>
#include <math.h>

// DisentangledStateEncoder on MI355X (gfx950).
// Phase 1 (MFMA bf16x3): per 64-row tile, one wave:
//   y = x@W1 + b1 (MFMA, bf16 hi/lo 3-term), LN+gelu fused epilogue (DPP-16),
//   ball = h@W_inn + b_inn (VALU+DPP), pre = h@Wc1_h + bc1 (MFMA via LDS h).
// Phase 2: sequential scan, one wave per batch row; all-VALU DPP reduction
//   (row_ror x4 + row_bcast15/31), single fast-tanh in lanes 48-52, readlane
//   broadcast. No LDS-pipe ops in the scan loop.
// B=512, T=512, D=128, H=64, S=5.

#define RS ((size_t)262144)

typedef __attribute__((ext_vector_type(8))) short bf16x8;
typedef __attribute__((ext_vector_type(4))) float f32x4;

__device__ __forceinline__ unsigned bf16_rne(float f){
    unsigned u = __float_as_uint(f);
    return (u + 0x7FFFu + ((u >> 16) & 1u)) >> 16;
}
__device__ __forceinline__ float bf16_to_f(unsigned h){ return __uint_as_float(h << 16); }
__device__ __forceinline__ float sigmoidf_(float v){ return 1.0f/(1.0f+expf(-v)); }

template<int CTRL>
__device__ __forceinline__ float dpp_add(float v){
    return v + __int_as_float(__builtin_amdgcn_update_dpp(
        0, __float_as_int(v), CTRL, 0xF, 0xF, false));
}
// full sum over each 16-lane row (all lanes receive it)
__device__ __forceinline__ float sum16(float v){
    v = dpp_add<0x121>(v); v = dpp_add<0x122>(v);
    v = dpp_add<0x124>(v); v = dpp_add<0x128>(v);
    return v;
}
__device__ __forceinline__ float rlane(float v, int l){
    return __int_as_float(__builtin_amdgcn_readlane(__float_as_int(v), l));
}

// ------------------------------------------------ weight pack (frag order)
// mfma_f32_16x16x32_bf16 A/B frag: lane l, elem e -> k = 4*(l>>4)+(e&3)+16*(e>>2),
// row/col = l&15.  Packed as [frag][half(hi,lo)][lane][8 shorts].
__global__ void dse_pack(const float* __restrict__ W1, const float* __restrict__ Wc1,
                         unsigned short* __restrict__ pw1, unsigned short* __restrict__ pw2){
    int t = blockIdx.x*256 + threadIdx.x;         // 0..1535
    if (t >= 1536) return;
    int lane = t & 63, frag = t >> 6;             // frag 0-15: W1, 16-23: W2
    int q = lane >> 4, m = lane & 15;
    int f  = (frag < 16) ? frag : frag - 16;
    int ks = f >> 2, nf = f & 3;
    unsigned short hi[8], lo[8];
    #pragma unroll
    for (int e = 0; e < 8; ++e){
        int k = ks*32 + 4*q + (e & 3) + 16*(e >> 2);
        float v = (frag < 16) ? W1[(size_t)k*64 + nf*16 + m]
                              : Wc1[(size_t)(5 + k)*64 + nf*16 + m];
        unsigned h = bf16_rne(v);
        hi[e] = (unsigned short)h;
        lo[e] = (unsigned short)bf16_rne(v - bf16_to_f(h));
    }
    unsigned short* dst = (frag < 16) ? pw1 : pw2;
    size_t b0 = ((size_t)(f*2 + 0)*64 + lane)*8;
    size_t b1 = ((size_t)(f*2 + 1)*64 + lane)*8;
    #pragma unroll
    for (int e = 0; e < 8; ++e){ dst[b0+e] = hi[e]; dst[b1+e] = lo[e]; }
}

// ------------------------------------------------ phase 1: 4096 blocks x 64
__global__ __launch_bounds__(64, 2) void dse_mfma1(
    const float* __restrict__ x,
    const unsigned short* __restrict__ pw1,
    const unsigned short* __restrict__ pw2,
    const float* __restrict__ b1, const float* __restrict__ ln_g,
    const float* __restrict__ ln_b, const float* __restrict__ W_inn,
    const float* __restrict__ b_inn, const float* __restrict__ bc1,
    float* __restrict__ pre, float* __restrict__ ball)
{
    __shared__ unsigned hbuf[64*64];          // h packed (hi<<16)|lo, swizzled
    const int lane = threadIdx.x;
    const int m = lane & 15, q = lane >> 4;
    const size_t row0 = (size_t)blockIdx.x * 64;
    const float* xb = x + row0*128;

    f32x4 acc[4][4];
    #pragma unroll
    for (int a = 0; a < 4; ++a)
        #pragma unroll
        for (int b = 0; b < 4; ++b) acc[a][b] = (f32x4){0.f,0.f,0.f,0.f};

    // ---- GEMM1: K=128 in 4 steps of 32, 3-term bf16 split
    #pragma unroll
    for (int ks = 0; ks < 4; ++ks){
        bf16x8 Bhi[4], Blo[4];
        #pragma unroll
        for (int nf = 0; nf < 4; ++nf){
            int fr = ks*4 + nf;
            Bhi[nf] = *(const bf16x8*)(pw1 + ((size_t)(fr*2+0)*64 + lane)*8);
            Blo[nf] = *(const bf16x8*)(pw1 + ((size_t)(fr*2+1)*64 + lane)*8);
        }
        bf16x8 Ahi[4], Alo[4];
        #pragma unroll
        for (int mf = 0; mf < 4; ++mf){
            const float* ap = xb + (size_t)(mf*16 + m)*128 + ks*32 + q*4;
            float4 L = *(const float4*)ap;
            float4 H = *(const float4*)(ap + 16);
            float v[8] = {L.x,L.y,L.z,L.w,H.x,H.y,H.z,H.w};
            bf16x8 h8, l8;
            #pragma unroll
            for (int e = 0; e < 8; ++e){
                unsigned hb = bf16_rne(v[e]);
                h8[e] = (short)hb;
                l8[e] = (short)bf16_rne(v[e] - bf16_to_f(hb));
            }
            Ahi[mf] = h8; Alo[mf] = l8;
        }
        #pragma unroll
        for (int mf = 0; mf < 4; ++mf)
            #pragma unroll
            for (int nf = 0; nf < 4; ++nf){
                acc[mf][nf] = __builtin_amdgcn_mfma_f32_16x16x32_bf16(Ahi[mf], Bhi[nf], acc[mf][nf], 0,0,0);
                acc[mf][nf] = __builtin_amdgcn_mfma_f32_16x16x32_bf16(Ahi[mf], Blo[nf], acc[mf][nf], 0,0,0);
                acc[mf][nf] = __builtin_amdgcn_mfma_f32_16x16x32_bf16(Alo[mf], Bhi[nf], acc[mf][nf], 0,0,0);
            }
    }

    // ---- per-lane params (col = nf*16 + m)
    float b1c[4], gcl[4], bcl[4], bc1c[4], wi[4][5];
    #pragma unroll
    for (int nf = 0; nf < 4; ++nf){
        int col = nf*16 + m;
        b1c[nf] = b1[col]; gcl[nf] = ln_g[col]; bcl[nf] = ln_b[col]; bc1c[nf] = bc1[col];
        #pragma unroll
        for (int i = 0; i < 5; ++i) wi[nf][i] = W_inn[(size_t)col*5 + i];
    }
    const float binsel = (m==0)?b_inn[0]:(m==1)?b_inn[1]:(m==2)?b_inn[2]:(m==3)?b_inn[3]:b_inn[4];

    // ---- epilogue per mf: bias + LN + gelu + ball + h->LDS
    // C layout: row = mf*16 + q*4 + e, col = nf*16 + m
    #pragma unroll
    for (int mf = 0; mf < 4; ++mf){
        float sum_[4], sq_[4];
        #pragma unroll
        for (int e = 0; e < 4; ++e){
            float s = 0.f, qq = 0.f;
            #pragma unroll
            for (int nf = 0; nf < 4; ++nf){
                float y = acc[mf][nf][e] + b1c[nf];
                acc[mf][nf][e] = y;
                s += y; qq = fmaf(y, y, qq);
            }
            sum_[e] = s; sq_[e] = qq;
        }
        #pragma unroll
        for (int e = 0; e < 4; ++e){ sum_[e] = sum16(sum_[e]); sq_[e] = sum16(sq_[e]); }

        float pb[4][5];
        #pragma unroll
        for (int e = 0; e < 4; ++e){
            float mu  = sum_[e] * (1.0f/64.0f);
            float var = fmaf(-mu, mu, sq_[e] * (1.0f/64.0f));
            float rs  = 1.0f / sqrtf(var + 1e-5f);
            #pragma unroll
            for (int i = 0; i < 5; ++i) pb[e][i] = 0.f;
            int r = mf*16 + q*4 + e;
            #pragma unroll
            for (int nf = 0; nf < 4; ++nf){
                float hn = fmaf((acc[mf][nf][e] - mu)*rs, gcl[nf], bcl[nf]);
                float ge = 0.5f*hn*(1.0f + erff(hn*0.70710678118654752f));
                unsigned hb = bf16_rne(ge);
                unsigned lb = bf16_rne(ge - bf16_to_f(hb));
                int c = nf*16 + m;
                hbuf[r*64 + (c ^ ((r & 7) << 2))] = (hb << 16) | lb;
                #pragma unroll
                for (int i = 0; i < 5; ++i) pb[e][i] = fmaf(ge, wi[nf][i], pb[e][i]);
            }
        }
        #pragma unroll
        for (int e = 0; e < 4; ++e)
            #pragma unroll
            for (int i = 0; i < 5; ++i) pb[e][i] = sum16(pb[e][i]);
        if (m < 5){
            #pragma unroll
            for (int e = 0; e < 4; ++e){
                int r = mf*16 + q*4 + e;
                float v = (m==0)?pb[e][0]:(m==1)?pb[e][1]:(m==2)?pb[e][2]:(m==3)?pb[e][3]:pb[e][4];
                ball[(row0 + r)*5 + m] = v + binsel;
            }
        }
    }
    __syncthreads();

    // ---- GEMM2: pre = h @ Wc1_h + bc1  (K=64, 2 steps, 3-term)
    f32x4 a2[4][4];
    #pragma unroll
    for (int a = 0; a < 4; ++a)
        #pragma unroll
        for (int b = 0; b < 4; ++b) a2[a][b] = (f32x4){0.f,0.f,0.f,0.f};

    #pragma unroll
    for (int ks = 0; ks < 2; ++ks){
        bf16x8 B2h[4], B2l[4];
        #pragma unroll
        for (int nf = 0; nf < 4; ++nf){
            int fr = ks*4 + nf;
            B2h[nf] = *(const bf16x8*)(pw2 + ((size_t)(fr*2+0)*64 + lane)*8);
            B2l[nf] = *(const bf16x8*)(pw2 + ((size_t)(fr*2+1)*64 + lane)*8);
        }
        bf16x8 A2h[4], A2l[4];
        #pragma unroll
        for (int mf = 0; mf < 4; ++mf){
            int r   = mf*16 + m;
            int sw  = (r & 7) << 2;
            int jb0 = ks*32 + 4*q;
            uint4 w0 = *(const uint4*)&hbuf[r*64 + (jb0 ^ sw)];
            uint4 w1 = *(const uint4*)&hbuf[r*64 + ((jb0 + 16) ^ sw)];
            int4 hv = make_int4(
                (int)__builtin_amdgcn_perm(w0.y, w0.x, 0x07060302u),
                (int)__builtin_amdgcn_perm(w0.w, w0.z, 0x07060302u),
                (int)__builtin_amdgcn_perm(w1.y, w1.x, 0x07060302u),
                (int)__builtin_amdgcn_perm(w1.w, w1.z, 0x07060302u));
            int4 lv = make_int4(
                (int)__builtin_amdgcn_perm(w0.y, w0.x, 0x05040100u),
                (int)__builtin_amdgcn_perm(w0.w, w0.z, 0x05040100u),
                (int)__builtin_amdgcn_perm(w1.y, w1.x, 0x05040100u),
                (int)__builtin_amdgcn_perm(w1.w, w1.z, 0x05040100u));
            A2h[mf] = __builtin_bit_cast(bf16x8, hv);
            A2l[mf] = __builtin_bit_cast(bf16x8, lv);
        }
        #pragma unroll
        for (int mf = 0; mf < 4; ++mf)
            #pragma unroll
            for (int nf = 0; nf < 4; ++nf){
                a2[mf][nf] = __builtin_amdgcn_mfma_f32_16x16x32_bf16(A2h[mf], B2h[nf], a2[mf][nf], 0,0,0);
                a2[mf][nf] = __builtin_amdgcn_mfma_f32_16x16x32_bf16(A2h[mf], B2l[nf], a2[mf][nf], 0,0,0);
                a2[mf][nf] = __builtin_amdgcn_mfma_f32_16x16x32_bf16(A2l[mf], B2h[nf], a2[mf][nf], 0,0,0);
            }
    }
    #pragma unroll
    for (int mf = 0; mf < 4; ++mf)
        #pragma unroll
        for (int nf = 0; nf < 4; ++nf)
            #pragma unroll
            for (int e = 0; e < 4; ++e)
                pre[(row0 + mf*16 + q*4 + e)*64 + nf*16 + m] = a2[mf][nf][e] + bc1c[nf];
}

// ------------------------------------------------ phase 2: 512 blocks x 64
__global__ __launch_bounds__(64) void dse_phase2(
    const float* __restrict__ pre,
    const float* __restrict__ ball,
    const float* __restrict__ Wc1,
    const float* __restrict__ Wc2,
    const float* __restrict__ bc2,
    const float* __restrict__ corr_scale,
    const float* __restrict__ raw_aL,
    const float* __restrict__ raw_aT,
    const float* __restrict__ raw_g,
    const float* __restrict__ raw_aR,
    const float* __restrict__ omega,
    float* __restrict__ out)
{
    const int lane = threadIdx.x;
    const int b    = blockIdx.x;

    const float w0c = Wc1[0*64+lane], w1c = Wc1[1*64+lane], w2c = Wc1[2*64+lane];
    const float w3c = Wc1[3*64+lane], w4c = Wc1[4*64+lane];
    const float v0 = Wc2[lane*5+0], v1 = Wc2[lane*5+1], v2 = Wc2[lane*5+2];
    const float v3 = Wc2[lane*5+3], v4 = Wc2[lane*5+4];
    // per-lane bc2 add for the single-tanh lane-select (lanes 48..52 own p0..p4)
    const float cadd = (lane==48)?bc2[0]:(lane==49)?bc2[1]:(lane==50)?bc2[2]
                      :(lane==51)?bc2[3]:(lane==52)?bc2[4]:0.0f;

    const float corr = corr_scale[0];
    const float aL = sigmoidf_(raw_aL[0])*0.15f + 0.85f;
    const float aT = sigmoidf_(raw_aT[0])*0.25f + 0.70f;
    const float gg = sigmoidf_(raw_g [0])*0.20f + 0.80f;
    const float aR = sigmoidf_(raw_aR[0])*0.40f;
    const float om = omega[0];
    const float gc  = gg*cosf(om), gs = gg*sinf(om), ngs = -gs;

    const float* prow = pre  + (size_t)b*512*64 + lane;   // coalesced per step
    const float* bb   = ball + (size_t)b*512*5;           // uniform per step

    float s0=0.f, s1=0.f, s2=0.f, s3=0.f, s4=0.f;

    float pc[4], bf[20];
    #pragma unroll
    for (int d = 0; d < 4; ++d) pc[d] = prow[d*64];
    #pragma unroll
    for (int w = 0; w < 5; ++w){
        float4 t = *(const float4*)&bb[w*4];
        bf[w*4+0]=t.x; bf[w*4+1]=t.y; bf[w*4+2]=t.z; bf[w*4+3]=t.w;
    }

    for (int tb = 0; tb < 128; ++tb) {
        const int tn = (tb < 127 ? tb + 1 : tb) * 4;
        float pn[4];
        #pragma unroll
        for (int d = 0; d < 4; ++d) pn[d] = prow[(size_t)(tn + d)*64];
        float4 n0 = *(const float4*)&bb[(size_t)tn*5 +  0];
        float4 n1 = *(const float4*)&bb[(size_t)tn*5 +  4];
        float4 n2 = *(const float4*)&bb[(size_t)tn*5 +  8];
        float4 n3 = *(const float4*)&bb[(size_t)tn*5 + 12];
        float4 n4 = *(const float4*)&bb[(size_t)tn*5 + 16];

        #pragma unroll
        for (int q = 0; q < 4; ++q) {
            float sl0 = fmaf(s0, aL, bf[q*5+0]);
            float sl1 = fmaf(s1, aT, bf[q*5+1]);
            float sl2 = fmaf(s2, gc,  fmaf(s3, gs,  bf[q*5+2]));
            float sl3 = fmaf(s3, gc,  fmaf(s2, ngs, bf[q*5+3]));
            float sl4 = fmaf(s4, aR, bf[q*5+4]);

            float u01 = fmaf(sl1, w1c, sl0*w0c);
            float u23 = fmaf(sl3, w3c, sl2*w2c);
            float u4p = fmaf(sl4, w4c, pc[q]);
            float u   = (u01 + u23) + u4p;
            float hm  = 0.5f*u*(1.0f + erff(u*0.70710678118654752f));

            // partials
            float p0 = hm*v0, p1 = hm*v1, p2 = hm*v2, p3 = hm*v3, p4 = hm*v4;
            // 16-lane row sums (all lanes), pure DPP-VALU
            p0 = dpp_add<0x121>(p0); p1 = dpp_add<0x121>(p1); p2 = dpp_add<0x121>(p2); p3 = dpp_add<0x121>(p3); p4 = dpp_add<0x121>(p4);
            p0 = dpp_add<0x122>(p0); p1 = dpp_add<0x122>(p1); p2 = dpp_add<0x122>(p2); p3 = dpp_add<0x122>(p3); p4 = dpp_add<0x122>(p4);
            p0 = dpp_add<0x124>(p0); p1 = dpp_add<0x124>(p1); p2 = dpp_add<0x124>(p2); p3 = dpp_add<0x124>(p3); p4 = dpp_add<0x124>(p4);
            p0 = dpp_add<0x128>(p0); p1 = dpp_add<0x128>(p1); p2 = dpp_add<0x128>(p2); p3 = dpp_add<0x128>(p3); p4 = dpp_add<0x128>(p4);
            // cross-row: lanes 48-63 accumulate the full 64-lane total
            p0 = dpp_add<0x142>(p0); p1 = dpp_add<0x142>(p1); p2 = dpp_add<0x142>(p2); p3 = dpp_add<0x142>(p3); p4 = dpp_add<0x142>(p4);
            p0 = dpp_add<0x143>(p0); p1 = dpp_add<0x143>(p1); p2 = dpp_add<0x143>(p2); p3 = dpp_add<0x143>(p3); p4 = dpp_add<0x143>(p4);

            // single fast tanh in lanes 48..52, then broadcast via readlane
            float vsel = (lane==49)?p1:(lane==50)?p2:(lane==51)?p3:(lane==52)?p4:p0;
            float targ = vsel + cadd;
            float e2   = __expf(2.0f*targ);
            float th   = 1.0f - 2.0f*__builtin_amdgcn_rcpf(e2 + 1.0f);
            float t0 = rlane(th,48), t1 = rlane(th,49), t2 = rlane(th,50);
            float t3 = rlane(th,51), t4 = rlane(th,52);

            s0 = fmaf(corr, t0, sl0);
            s1 = fmaf(corr, t1, sl1);
            s2 = fmaf(corr, t2, sl2);
            s3 = fmaf(corr, t3, sl3);
            s4 = fmaf(corr, t4, sl4);
        }

        #pragma unroll
        for (int d = 0; d < 4; ++d) pc[d] = pn[d];
        bf[0]=n0.x; bf[1]=n0.y; bf[2]=n0.z; bf[3]=n0.w;
        bf[4]=n1.x; bf[5]=n1.y; bf[6]=n1.z; bf[7]=n1.w;
        bf[8]=n2.x; bf[9]=n2.y; bf[10]=n2.z; bf[11]=n2.w;
        bf[12]=n3.x; bf[13]=n3.y; bf[14]=n3.z; bf[15]=n3.w;
        bf[16]=n4.x; bf[17]=n4.y; bf[18]=n4.z; bf[19]=n4.w;
    }

    if (lane < 5) {
        float v = (lane==0)?s0 : (lane==1)?s1 : (lane==2)?s2 : (lane==3)?s3 : s4;
        out[b*5 + lane] = v;
    }
}

// ------------------------------------------------ launch
extern "C" void kernel_launch(void* const* d_in, const int* in_sizes, int n_in,
                              void* d_out, int out_size, void* d_ws, size_t ws_size,
                              hipStream_t stream) {
    const float* x     = (const float*)d_in[0];
    const float* W1    = (const float*)d_in[1];
    const float* b1    = (const float*)d_in[2];
    const float* ln_g  = (const float*)d_in[3];
    const float* ln_b  = (const float*)d_in[4];
    const float* W_inn = (const float*)d_in[5];
    const float* b_inn = (const float*)d_in[6];
    const float* Wc1   = (const float*)d_in[7];
    const float* bc1   = (const float*)d_in[8];
    const float* Wc2   = (const float*)d_in[9];
    const float* bc2   = (const float*)d_in[10];
    const float* corr  = (const float*)d_in[11];
    const float* raL   = (const float*)d_in[12];
    const float* raT   = (const float*)d_in[13];
    const float* rg    = (const float*)d_in[14];
    const float* raR   = (const float*)d_in[15];
    const float* om    = (const float*)d_in[16];

    float* pre  = (float*)d_ws;                          // 64 MiB
    float* ball = pre + RS*64;                           // 5 MiB
    unsigned short* pw1 = (unsigned short*)(ball + RS*5);// 32 KiB (16 frags x2x64x8)
    unsigned short* pw2 = pw1 + 16*2*64*8;               // 16 KiB (8 frags x2x64x8)

    dse_pack<<<6, 256, 0, stream>>>(W1, Wc1, pw1, pw2);
    dse_mfma1<<<4096, 64, 0, stream>>>(x, pw1, pw2, b1, ln_g, ln_b, W_inn, b_inn,
                                       bc1, pre, ball);
    dse_phase2<<<512, 64, 0, stream>>>(pre, ball, Wc1, Wc2, bc2, corr,
                                       raL, raT, rg, raR, om, (float*)d_out);
}